// Round 3
// baseline (2158.561 us; speedup 1.0000x reference)
//
#include <hip/hip_runtime.h>
#include <math.h>

#define T_ENC 2048
#define BATCH 32
#define DM    256
#define HID   512
#define VOC   32
#define LEN   100
#define NBLK  128
#define NTHR  512

// ws layout (floats):
// [0,      65536)    enc_score -> (after softmax, in place) aw [b][t]
// [65536, 196608)    ctx_part [tg][b][d]
// [196608,204800)    ctx [b][d]
// [204800,253952)    gi_const [b][1536]
// [253952,303104)    gi_emb   [v][1536]
// [303104,1957888)   h bufs: 101 x [b][k] (32x512)  -- fresh buffer per step
// [1957888]          barrier counter (int)

// ---------- precompute ----------

__global__ void k_score(const float* __restrict__ enc, const float* __restrict__ Wattn,
                        float* __restrict__ score) {
  int wid  = (blockIdx.x * blockDim.x + threadIdx.x) >> 6;
  int lane = threadIdx.x & 63;
  int b = wid & 31, t = wid >> 5;
  const float4 e4 = *(const float4*)(enc + (size_t)(t * BATCH + b) * DM + lane * 4);
  const float4 w4 = *(const float4*)(Wattn + HID + lane * 4);
  float v = e4.x * w4.x + e4.y * w4.y + e4.z * w4.z + e4.w * w4.w;
  for (int o = 32; o; o >>= 1) v += __shfl_down(v, o);
  if (lane == 0) score[b * T_ENC + t] = v;
}

__global__ void k_softmax(float* __restrict__ score) {
  int b = blockIdx.x, tid = threadIdx.x;
  float* row = score + b * T_ENC;
  float4 v0 = *(const float4*)(row + tid * 8);
  float4 v1 = *(const float4*)(row + tid * 8 + 4);
  float m = fmaxf(fmaxf(fmaxf(v0.x, v0.y), fmaxf(v0.z, v0.w)),
                  fmaxf(fmaxf(v1.x, v1.y), fmaxf(v1.z, v1.w)));
  for (int o = 32; o; o >>= 1) m = fmaxf(m, __shfl_xor(m, o));
  __shared__ float redm[8];
  __shared__ float reds[8];
  if ((tid & 63) == 0) redm[tid >> 6] = m;
  __syncthreads();
  m = fmaxf(fmaxf(redm[0], redm[1]), fmaxf(redm[2], redm[3]));
  float e0 = expf(v0.x - m), e1 = expf(v0.y - m), e2 = expf(v0.z - m), e3 = expf(v0.w - m);
  float e4 = expf(v1.x - m), e5 = expf(v1.y - m), e6 = expf(v1.z - m), e7 = expf(v1.w - m);
  float s = ((e0 + e1) + (e2 + e3)) + ((e4 + e5) + (e6 + e7));
  for (int o = 32; o; o >>= 1) s += __shfl_xor(s, o);
  if ((tid & 63) == 0) reds[tid >> 6] = s;
  __syncthreads();
  s = (reds[0] + reds[1]) + (reds[2] + reds[3]);
  float inv = 1.f / s;
  float4 o0 = {e0 * inv, e1 * inv, e2 * inv, e3 * inv};
  float4 o1 = {e4 * inv, e5 * inv, e6 * inv, e7 * inv};
  *(float4*)(row + tid * 8)     = o0;
  *(float4*)(row + tid * 8 + 4) = o1;
}

__global__ void k_ctxpart(const float* __restrict__ enc, const float* __restrict__ aw,
                          float* __restrict__ ctx_part) {
  int b = blockIdx.x >> 4, tg = blockIdx.x & 15;
  int w = threadIdx.x >> 6, lane = threadIdx.x & 63;
  float4 acc = {0.f, 0.f, 0.f, 0.f};
  for (int i = 0; i < 32; ++i) {
    int t = tg * 128 + w * 32 + i;
    float a = aw[b * T_ENC + t];
    const float4 e4 = *(const float4*)(enc + (size_t)(t * BATCH + b) * DM + lane * 4);
    acc.x += a * e4.x; acc.y += a * e4.y; acc.z += a * e4.z; acc.w += a * e4.w;
  }
  __shared__ float4 part[4][64];
  part[w][lane] = acc;
  __syncthreads();
  if (w == 0) {
    float4 s = part[0][lane], p1 = part[1][lane], p2 = part[2][lane], p3 = part[3][lane];
    s.x += p1.x + p2.x + p3.x; s.y += p1.y + p2.y + p3.y;
    s.z += p1.z + p2.z + p3.z; s.w += p1.w + p2.w + p3.w;
    *(float4*)(ctx_part + (size_t)(tg * BATCH + b) * DM + lane * 4) = s;
  }
}

__global__ void k_ctxreduce(const float* __restrict__ ctx_part, float* __restrict__ ctx) {
  int b = blockIdx.x, d = threadIdx.x;
  float s = 0.f;
  for (int tg = 0; tg < 16; ++tg) s += ctx_part[(size_t)(tg * BATCH + b) * DM + d];
  ctx[b * DM + d] = s;
}

__global__ void k_gitab(const float* __restrict__ Wih, const float* __restrict__ bih,
                        const float* __restrict__ emb, const float* __restrict__ ctx,
                        float* __restrict__ gi_const, float* __restrict__ gi_emb) {
  int idx = threadIdx.x & 31, rs = threadIdx.x >> 5;
  int row = blockIdx.x * 8 + rs;
  const float* wr = Wih + (size_t)row * (2 * DM);
  const float* c = ctx + idx * DM;
  const float* e = emb + idx * DM;
  float accC = 0.f, accE = 0.f;
  for (int k = 0; k < DM; k += 4) {
    float4 we = *(const float4*)(wr + k);
    float4 wc = *(const float4*)(wr + DM + k);
    float4 cv = *(const float4*)(c + k);
    float4 ev = *(const float4*)(e + k);
    accE += we.x * ev.x + we.y * ev.y + we.z * ev.z + we.w * ev.w;
    accC += wc.x * cv.x + wc.y * cv.y + wc.z * cv.z + wc.w * cv.w;
  }
  gi_const[idx * 1536 + row] = accC + bih[row];
  gi_emb[idx * 1536 + row]   = accE;
}

__global__ void k_init(float* __restrict__ h0, float* __restrict__ out,
                       const float* __restrict__ b_out, int* __restrict__ counter) {
  int i = blockIdx.x * blockDim.x + threadIdx.x;
  if (i < HID * BATCH) h0[i] = 0.f;
  if (i == 0) *counter = 0;
  for (int j = i; j < BATCH * LEN * VOC; j += gridDim.x * blockDim.x)
    out[j] = b_out[j & 31];
}

// ---------- persistent recurrence ----------
// 128 blocks x 512 threads. Block bk owns h-dims [bk*4, bk*4+4).
// thread: b = tid&31, q = tid>>5 in [0,16): dd = q&3, ks = q>>2 (k-quarter).
// Each thread computes 3 gate-dot partials (128 MACs each) sharing one h stream.
__global__ __launch_bounds__(NTHR) void k_seq(
    const float* __restrict__ Whh, const float* __restrict__ bhh,
    const float* __restrict__ Wout,
    const float* __restrict__ gic, const float* __restrict__ gie,
    float* __restrict__ hbufs, int* __restrict__ counter,
    float* __restrict__ out) {
  const int tid = threadIdx.x, bk = blockIdx.x;
  const int b = tid & 31, q = tid >> 5;
  const int dd = q & 3, ks = q >> 2;
  const int d4 = bk * 4;

  __shared__ float gh_part[4][3][4][BATCH];
  __shared__ float hnew_lds[4][BATCH];
  __shared__ unsigned long long keyLds[BATCH][8];
  __shared__ int tokLds[BATCH];

  // W_hh row slices for this thread (L1-resident across steps: 24.6 KB/block)
  const float* wr0 = Whh + (size_t)(          d4 + dd) * HID + ks * 128;
  const float* wr1 = Whh + (size_t)(HID     + d4 + dd) * HID + ks * 128;
  const float* wr2 = Whh + (size_t)(2 * HID + d4 + dd) * HID + ks * 128;

  // pred weights preloaded once: this thread handles (pb0, pv) and (pb1, pv)
  const int pv  = tid & 31;
  const int pb0 = tid >> 5;       // 0..15
  const int pb1 = pb0 + 16;       // 16..31
  const float4 wo4 = *(const float4*)(Wout + (size_t)pv * HID + d4);

  // phase-2 per-thread constants (only tid<128 uses them)
  float bh0 = 0.f, bh1 = 0.f, bh2 = 0.f;
  if (tid < 128) {
    int d = d4 + (tid >> 5);
    bh0 = bhh[d]; bh1 = bhh[HID + d]; bh2 = bhh[2 * HID + d];
  }
  const float* gcb = gic + (size_t)b * 1536;

  for (int s = 0; s < LEN; ++s) {
    const float* hc = hbufs + (size_t)s * (HID * BATCH);

    // ---- token argmax of pred[:, s-1, :] (parallel, redundant per block) ----
    if (s == 0) {
      if (tid < BATCH) tokLds[tid] = 1;  // SOS
    } else {
      if (tid < 256) {
        const int bb = tid >> 3, j = tid & 7;
        const float* p = out + (size_t)(bb * LEN + (s - 1)) * VOC + j * 4;
        unsigned long long best = 0ull;
#pragma unroll
        for (int u = 0; u < 4; ++u) {
          unsigned xi = __float_as_uint(p[u]);
          xi = (xi & 0x80000000u) ? ~xi : (xi | 0x80000000u);
          unsigned long long key =
              ((unsigned long long)xi << 6) | (unsigned long long)(63 - (j * 4 + u));
          best = key > best ? key : best;
        }
        keyLds[bb][j] = best;
      }
      __syncthreads();
      if (tid < BATCH) {
        unsigned long long m = keyLds[tid][0];
#pragma unroll
        for (int j2 = 1; j2 < 8; ++j2) {
          unsigned long long k2 = keyLds[tid][j2];
          m = k2 > m ? k2 : m;
        }
        tokLds[tid] = 63 - (int)(m & 63ull);
      }
    }

    // ---- gh partial dots: 3 gates x 128 MACs per thread ----
    const float* hp = hc + b * HID + ks * 128;
    float r0 = 0, r1 = 0, r2 = 0, r3 = 0;
    float z0 = 0, z1 = 0, z2 = 0, z3 = 0;
    float n0 = 0, n1 = 0, n2 = 0, n3 = 0;
#pragma unroll 4
    for (int k = 0; k < 128; k += 4) {
      const float4 h4 = *(const float4*)(hp + k);
      const float4 w0 = *(const float4*)(wr0 + k);
      const float4 w1 = *(const float4*)(wr1 + k);
      const float4 w2 = *(const float4*)(wr2 + k);
      r0 += w0.x * h4.x; r1 += w0.y * h4.y; r2 += w0.z * h4.z; r3 += w0.w * h4.w;
      z0 += w1.x * h4.x; z1 += w1.y * h4.y; z2 += w1.z * h4.z; z3 += w1.w * h4.w;
      n0 += w2.x * h4.x; n1 += w2.y * h4.y; n2 += w2.z * h4.z; n3 += w2.w * h4.w;
    }
    gh_part[ks][0][dd][b] = (r0 + r1) + (r2 + r3);
    gh_part[ks][1][dd][b] = (z0 + z1) + (z2 + z3);
    gh_part[ks][2][dd][b] = (n0 + n1) + (n2 + n3);
    __syncthreads();

    // ---- gates + h_new (tid < 128) ----
    if (tid < 128) {
      const int slot = tid >> 5;
      const int d = d4 + slot;
      const int tk = tokLds[b];
      const float* ge = gie + (size_t)tk * 1536;
      float gir = ge[d]            + gcb[d];
      float giz = ge[HID + d]      + gcb[HID + d];
      float gin = ge[2 * HID + d]  + gcb[2 * HID + d];
      float ghr = ((gh_part[0][0][slot][b] + gh_part[1][0][slot][b]) +
                   (gh_part[2][0][slot][b] + gh_part[3][0][slot][b])) + bh0;
      float ghz = ((gh_part[0][1][slot][b] + gh_part[1][1][slot][b]) +
                   (gh_part[2][1][slot][b] + gh_part[3][1][slot][b])) + bh1;
      float ghn = ((gh_part[0][2][slot][b] + gh_part[1][2][slot][b]) +
                   (gh_part[2][2][slot][b] + gh_part[3][2][slot][b])) + bh2;
      float r = 1.f / (1.f + expf(-(gir + ghr)));
      float z = 1.f / (1.f + expf(-(giz + ghz)));
      float n = tanhf(gin + r * ghn);
      float hold = hc[(size_t)b * HID + d];
      float hn = (1.f - z) * n + z * hold;
      hbufs[(size_t)(s + 1) * (HID * BATCH) + b * HID + d] = hn;  // fresh buffer
      hnew_lds[slot][b] = hn;
    }
    __syncthreads();

    // ---- pred partials: 2 atomics per thread, W_out rows in registers ----
    {
      float ca = hnew_lds[0][pb0] * wo4.x + hnew_lds[1][pb0] * wo4.y +
                 hnew_lds[2][pb0] * wo4.z + hnew_lds[3][pb0] * wo4.w;
      atomicAdd(out + (size_t)(pb0 * LEN + s) * VOC + pv, ca);
      float cb = hnew_lds[0][pb1] * wo4.x + hnew_lds[1][pb1] * wo4.y +
                 hnew_lds[2][pb1] * wo4.z + hnew_lds[3][pb1] * wo4.w;
      atomicAdd(out + (size_t)(pb1 * LEN + s) * VOC + pv, cb);
    }

    // ---- grid barrier (release add + relaxed spin; fresh-address protocol
    //      means no acquire-invalidate needed -> L1 weight residency kept) ----
    if (s < LEN - 1) {
      __syncthreads();  // all waves drain vmcnt before s_barrier (compiler emits)
      if (tid == 0) {
        __hip_atomic_fetch_add(counter, 1, __ATOMIC_RELEASE, __HIP_MEMORY_SCOPE_AGENT);
        const int target = NBLK * (s + 1);
        while (__hip_atomic_load(counter, __ATOMIC_RELAXED, __HIP_MEMORY_SCOPE_AGENT) < target)
          __builtin_amdgcn_s_sleep(2);
      }
      __syncthreads();
      __builtin_amdgcn_fence(__ATOMIC_ACQUIRE, "workgroup");  // compiler ordering only
    }
  }
}

extern "C" void kernel_launch(void* const* d_in, const int* in_sizes, int n_in,
                              void* d_out, int out_size, void* d_ws, size_t ws_size,
                              hipStream_t stream) {
  (void)in_sizes; (void)n_in; (void)out_size; (void)ws_size;
  const float* enc   = (const float*)d_in[0];
  const float* emb   = (const float*)d_in[1];
  const float* Wattn = (const float*)d_in[2];
  // d_in[3] b_attn: constant shift, cancels in softmax
  const float* Wih  = (const float*)d_in[4];
  const float* Whh  = (const float*)d_in[5];
  const float* bih  = (const float*)d_in[6];
  const float* bhh  = (const float*)d_in[7];
  const float* Wout = (const float*)d_in[8];
  const float* bout = (const float*)d_in[9];

  float* ws       = (float*)d_ws;
  float* score    = ws;               // 65536
  float* ctx_part = ws + 65536;       // 131072
  float* ctx      = ws + 196608;      // 8192
  float* gic      = ws + 204800;      // 49152
  float* gie      = ws + 253952;      // 49152
  float* hbufs    = ws + 303104;      // 101 * 16384
  int*   counter  = (int*)(ws + 1957888);
  float* out      = (float*)d_out;

  k_init<<<64, 256, 0, stream>>>(hbufs, out, bout, counter);
  k_score<<<16384, 256, 0, stream>>>(enc, Wattn, score);
  k_softmax<<<32, 256, 0, stream>>>(score);
  k_ctxpart<<<512, 256, 0, stream>>>(enc, score, ctx_part);
  k_ctxreduce<<<32, 256, 0, stream>>>(ctx_part, ctx);
  k_gitab<<<192, 256, 0, stream>>>(Wih, bih, emb, ctx, gic, gie);

  k_seq<<<NBLK, NTHR, 0, stream>>>(Whh, bhh, Wout, gic, gie, hbufs, counter, out);
}